// Round 3
// baseline (332.924 us; speedup 1.0000x reference)
//
#include <hip/hip_runtime.h>

typedef short bf16x8 __attribute__((ext_vector_type(8)));
typedef float f32x4  __attribute__((ext_vector_type(4)));

#define NSTEP 25
#define SROW  264               // padded LDS row stride in shorts
#define LDSB  (32 * SROW)       // shorts per buffer (32 rows)

__device__ __forceinline__ unsigned short f2bf(float x) {
    union { float f; unsigned int u; } v; v.f = x;
    unsigned int r = v.u + 0x7FFFu + ((v.u >> 16) & 1u);   // RNE
    return (unsigned short)(r >> 16);
}

#if __has_builtin(__builtin_amdgcn_cvt_pk_bf16_f32)
typedef __bf16 bfv2 __attribute__((ext_vector_type(2)));
__device__ __forceinline__ unsigned int pk2bf(float a, float b) {
    union { bfv2 v; unsigned int u; } c;
    c.v = __builtin_amdgcn_cvt_pk_bf16_f32(a, b);   // lo=a, hi=b, RNE
    return c.u;
}
#else
__device__ __forceinline__ unsigned int pk2bf(float a, float b) {
    return (unsigned int)f2bf(a) | ((unsigned int)f2bf(b) << 16);
}
#endif

__device__ __forceinline__ float tanh_fast(float x) {
    float e = __expf(2.0f * x);
    return 1.0f - 2.0f * __builtin_amdgcn_rcpf(e + 1.0f);
}

// sigma-permuted, fragment-ordered bf16 weights (R2 layout, verified):
// Wr[kc*8192 + n*32 + q*8 + j] = W[sigma_inv(kc*32+q*8+j)][n]
// sigma_inv(p) = (p & ~31) | ((p&1)<<4) | ((p>>1)&15)
__global__ void prep_weights(const float* __restrict__ W1,
                             const float* __restrict__ W2,
                             unsigned short* __restrict__ Wr)
{
    int b = blockIdx.x;
    const float* src = (b < 256) ? W1 : W2;
    unsigned short* dst = Wr + ((b < 256) ? 0 : 65536);
    int idx = (b & 255) * 256 + threadIdx.x;
    int j  = idx & 7;
    int q  = (idx >> 3) & 3;
    int n  = (idx >> 5) & 255;
    int kc = idx >> 13;
    int p  = kc * 32 + q * 8 + j;
    int k  = (p & ~31) | ((p & 1) << 4) | ((p >> 1) & 15);
    dst[idx] = f2bf(src[k * 256 + n]);
}

// Block i<256: row i of W21 = W2@W1 (fp32), scattered into frag layout.
// Block 256:  c1 = b2@W1 (fp32 vector).
__global__ void prep_w21(const float* __restrict__ W1,
                         const float* __restrict__ W2,
                         const float* __restrict__ b2,
                         unsigned short* __restrict__ W21r,
                         float* __restrict__ c1)
{
    __shared__ float row[256];
    int i = blockIdx.x, j = threadIdx.x;
    row[j] = (i < 256) ? W2[i * 256 + j] : b2[j];
    __syncthreads();
    float acc = 0.f;
    for (int d = 0; d < 256; ++d)
        acc = fmaf(row[d], W1[d * 256 + j], acc);
    if (i < 256) {
        // forward sigma: k-row i -> packed position p
        int p  = (i & ~31) | ((i & 15) << 1) | ((i >> 4) & 1);
        int kc = p >> 5, q = (p >> 3) & 3, jj = p & 7;
        W21r[kc * 8192 + j * 32 + q * 8 + jj] = f2bf(acc);
    } else {
        c1[j] = acc;
    }
}

// 256 threads = 4 waves; wave w owns cols [64w, 64w+64) of the block's 32 rows.
// Loop state: y = z@W1 (fp32 C-layout regs), S = sum of H (fp32).
// One GEMM (H @ W21, weights register-resident) per step.
__global__ __launch_bounds__(256, 2) void ode_main(
    const float* __restrict__ z0,
    const float* __restrict__ t_range,
    const float* __restrict__ b1,
    const float* __restrict__ wt,
    const float* __restrict__ b2,
    const unsigned short* __restrict__ W1r,
    const unsigned short* __restrict__ W2r,
    const unsigned short* __restrict__ W21r,
    const float* __restrict__ c1,
    float* __restrict__ out)
{
    __shared__ __align__(16) unsigned short As[2 * LDSB];   // 33 KiB double-buffered

    const int tid  = threadIdx.x;
    const int wave = tid >> 6;        // 0..3
    const int lane = tid & 63;
    const int q    = lane >> 4;
    const int l15  = lane & 15;
    const int row0 = blockIdx.x * 32;
    const int n0   = wave * 64;

    float b1v[4], wtv[4], c1v[4];
#pragma unroll
    for (int tt = 0; tt < 4; ++tt) {
        int n = n0 + tt * 16 + l15;
        b1v[tt] = b1[n]; wtv[tt] = wt[n]; c1v[tt] = c1[n];
    }
    const float dt = t_range[1] - t_range[0];

    // ---- stage bf16(z0) into buf0 ----
#pragma unroll
    for (int band = 0; band < 2; ++band)
#pragma unroll
        for (int r = 0; r < 4; ++r) {
            int m = band * 16 + q * 4 + r;
            const float* zr = &z0[(row0 + m) * 256 + n0];
            *(unsigned int*)&As[m * SROW + n0 + l15 * 2] =
                pk2bf(zr[l15], zr[16 + l15]);
            *(unsigned int*)&As[m * SROW + n0 + 32 + l15 * 2] =
                pk2bf(zr[32 + l15], zr[48 + l15]);
        }
    __syncthreads();

    // ---- y0 = z0 @ W1 (B-frags streamed from global, used once) ----
    f32x4 y[2][4];
#pragma unroll
    for (int band = 0; band < 2; ++band)
#pragma unroll
        for (int tt = 0; tt < 4; ++tt) y[band][tt] = f32x4{0.f, 0.f, 0.f, 0.f};
#pragma unroll
    for (int kc = 0; kc < 8; ++kc) {
        bf16x8 a[2];
#pragma unroll
        for (int band = 0; band < 2; ++band)
            a[band] = *(const bf16x8*)&As[(band * 16 + l15) * SROW + kc * 32 + q * 8];
#pragma unroll
        for (int tt = 0; tt < 4; ++tt) {
            bf16x8 bb = *(const bf16x8*)&W1r[kc * 8192 + (n0 + tt * 16 + l15) * 32 + q * 8];
#pragma unroll
            for (int band = 0; band < 2; ++band)
                y[band][tt] = __builtin_amdgcn_mfma_f32_16x16x32_bf16(
                    a[band], bb, y[band][tt], 0, 0, 0);
        }
    }

    // ---- preload W21 fragments (128 VGPRs), resident for the whole loop ----
    bf16x8 w21f[8][4];
#pragma unroll
    for (int kc = 0; kc < 8; ++kc)
#pragma unroll
        for (int tt = 0; tt < 4; ++tt)
            w21f[kc][tt] = *(const bf16x8*)&W21r[kc * 8192 + (n0 + tt * 16 + l15) * 32 + q * 8];

    f32x4 S[2][4];
#pragma unroll
    for (int band = 0; band < 2; ++band)
#pragma unroll
        for (int tt = 0; tt < 4; ++tt) S[band][tt] = f32x4{0.f, 0.f, 0.f, 0.f};

    for (int s = 0; s < NSTEP; ++s) {
        const float t = t_range[s];
        // bt folds b1 + t*wt + s*dt*c1 (the accumulated c1 drift of y)
        float bt[4];
#pragma unroll
        for (int tt = 0; tt < 4; ++tt)
            bt[tt] = b1v[tt] + t * wtv[tt] + (s * dt) * c1v[tt];

        if (s < NSTEP - 1) {
            const int buf = ((s + 1) & 1) * LDSB;
            // H = tanh(y + bt); S += H; stage bf16(H)
#pragma unroll
            for (int band = 0; band < 2; ++band)
#pragma unroll
                for (int r = 0; r < 4; ++r) {
                    int m = band * 16 + q * 4 + r;
                    float h0 = tanh_fast(y[band][0][r] + bt[0]);
                    float h1 = tanh_fast(y[band][1][r] + bt[1]);
                    float h2 = tanh_fast(y[band][2][r] + bt[2]);
                    float h3 = tanh_fast(y[band][3][r] + bt[3]);
                    S[band][0][r] += h0; S[band][1][r] += h1;
                    S[band][2][r] += h2; S[band][3][r] += h3;
                    *(unsigned int*)&As[buf + m * SROW + n0 + l15 * 2]      = pk2bf(h0, h1);
                    *(unsigned int*)&As[buf + m * SROW + n0 + 32 + l15 * 2] = pk2bf(h2, h3);
                }
            __syncthreads();

            // y += dt * (H @ W21)
            f32x4 acc[2][4];
#pragma unroll
            for (int band = 0; band < 2; ++band)
#pragma unroll
                for (int tt = 0; tt < 4; ++tt) acc[band][tt] = f32x4{0.f, 0.f, 0.f, 0.f};
#pragma unroll
            for (int kc = 0; kc < 8; ++kc) {
                bf16x8 a[2];
#pragma unroll
                for (int band = 0; band < 2; ++band)
                    a[band] = *(const bf16x8*)&As[buf + (band * 16 + l15) * SROW + kc * 32 + q * 8];
#pragma unroll
                for (int band = 0; band < 2; ++band)
#pragma unroll
                    for (int tt = 0; tt < 4; ++tt)
                        acc[band][tt] = __builtin_amdgcn_mfma_f32_16x16x32_bf16(
                            a[band], w21f[kc][tt], acc[band][tt], 0, 0, 0);
            }
#pragma unroll
            for (int band = 0; band < 2; ++band)
#pragma unroll
                for (int tt = 0; tt < 4; ++tt)
#pragma unroll
                    for (int r = 0; r < 4; ++r)
                        y[band][tt][r] += dt * acc[band][tt][r];
        } else {
            // last step: H only feeds S
#pragma unroll
            for (int band = 0; band < 2; ++band)
#pragma unroll
                for (int r = 0; r < 4; ++r)
#pragma unroll
                    for (int tt = 0; tt < 4; ++tt)
                        S[band][tt][r] += tanh_fast(y[band][tt][r] + bt[tt]);
        }
    }

    // ---- epilogue: z_T = z0 + dt*(S @ W2) + NSTEP*dt*b2 ----
    {
        const int buf = (NSTEP & 1) * LDSB;   // buf1 (last H used buf0)
#pragma unroll
        for (int band = 0; band < 2; ++band)
#pragma unroll
            for (int r = 0; r < 4; ++r) {
                int m = band * 16 + q * 4 + r;
                *(unsigned int*)&As[buf + m * SROW + n0 + l15 * 2] =
                    pk2bf(S[band][0][r], S[band][1][r]);
                *(unsigned int*)&As[buf + m * SROW + n0 + 32 + l15 * 2] =
                    pk2bf(S[band][2][r], S[band][3][r]);
            }
        __syncthreads();

        f32x4 acc[2][4];
#pragma unroll
        for (int band = 0; band < 2; ++band)
#pragma unroll
            for (int tt = 0; tt < 4; ++tt) acc[band][tt] = f32x4{0.f, 0.f, 0.f, 0.f};
#pragma unroll
        for (int kc = 0; kc < 8; ++kc) {
            bf16x8 a[2];
#pragma unroll
            for (int band = 0; band < 2; ++band)
                a[band] = *(const bf16x8*)&As[buf + (band * 16 + l15) * SROW + kc * 32 + q * 8];
#pragma unroll
            for (int tt = 0; tt < 4; ++tt) {
                bf16x8 bb = *(const bf16x8*)&W2r[kc * 8192 + (n0 + tt * 16 + l15) * 32 + q * 8];
#pragma unroll
                for (int band = 0; band < 2; ++band)
                    acc[band][tt] = __builtin_amdgcn_mfma_f32_16x16x32_bf16(
                        a[band], bb, acc[band][tt], 0, 0, 0);
            }
        }

        const float cb2 = (float)NSTEP * dt;
#pragma unroll
        for (int band = 0; band < 2; ++band)
#pragma unroll
            for (int tt = 0; tt < 4; ++tt) {
                float b2v = b2[n0 + tt * 16 + l15];
#pragma unroll
                for (int r = 0; r < 4; ++r) {
                    int idx = (row0 + band * 16 + q * 4 + r) * 256 + n0 + tt * 16 + l15;
                    out[idx] = z0[idx] + dt * acc[band][tt][r] + cb2 * b2v;
                }
            }
    }
}

extern "C" void kernel_launch(void* const* d_in, const int* in_sizes, int n_in,
                              void* d_out, int out_size, void* d_ws, size_t ws_size,
                              hipStream_t stream) {
    const float* z0      = (const float*)d_in[0];
    const float* t_range = (const float*)d_in[1];
    const float* W1      = (const float*)d_in[2];
    const float* b1      = (const float*)d_in[3];
    const float* wt      = (const float*)d_in[4];
    const float* W2      = (const float*)d_in[5];
    const float* b2      = (const float*)d_in[6];

    unsigned short* Wr = (unsigned short*)d_ws;
    // shorts: W1r [0,65536)  W2r [65536,131072)  W21r [131072,196608); then c1 (256 floats)
    unsigned short* W1r  = Wr;
    unsigned short* W2r  = Wr + 65536;
    unsigned short* W21r = Wr + 131072;
    float*          c1   = (float*)(Wr + 196608);

    prep_weights<<<512, 256, 0, stream>>>(W1, W2, Wr);
    prep_w21<<<257, 256, 0, stream>>>(W1, W2, b2, W21r, c1);
    ode_main<<<512, 256, 0, stream>>>(z0, t_range, b1, wt, b2,
                                      W1r, W2r, W21r, c1, (float*)d_out);
}

// Round 4
// 158.239 us; speedup vs baseline: 2.1039x; 2.1039x over previous
//
#include <hip/hip_runtime.h>

typedef short bf16x8 __attribute__((ext_vector_type(8)));
typedef float f32x4  __attribute__((ext_vector_type(4)));

#define NSTEP 25
#define SROW  264               // padded LDS row stride in shorts
#define LDSB  (32 * SROW)       // shorts per buffer (32 rows)

__device__ __forceinline__ unsigned short f2bf(float x) {
    union { float f; unsigned int u; } v; v.f = x;
    unsigned int r = v.u + 0x7FFFu + ((v.u >> 16) & 1u);   // RNE
    return (unsigned short)(r >> 16);
}

#if __has_builtin(__builtin_amdgcn_cvt_pk_bf16_f32)
typedef __bf16 bfv2 __attribute__((ext_vector_type(2)));
__device__ __forceinline__ unsigned int pk2bf(float a, float b) {
    union { bfv2 v; unsigned int u; } c;
    c.v = __builtin_amdgcn_cvt_pk_bf16_f32(a, b);   // lo=a, hi=b, RNE
    return c.u;
}
#else
__device__ __forceinline__ unsigned int pk2bf(float a, float b) {
    return (unsigned int)f2bf(a) | ((unsigned int)f2bf(b) << 16);
}
#endif

__device__ __forceinline__ float tanh_fast(float x) {
    float e = __expf(2.0f * x);
    return 1.0f - 2.0f * __builtin_amdgcn_rcpf(e + 1.0f);
}

// sigma-permuted, fragment-ordered bf16 weights (verified layout):
// Wr[kc*8192 + n*32 + q*8 + j] = W[sigma_inv(kc*32+q*8+j)][n]
// sigma_inv(p) = (p & ~31) | ((p&1)<<4) | ((p>>1)&15)
__global__ void prep_weights(const float* __restrict__ W1,
                             const float* __restrict__ W2,
                             unsigned short* __restrict__ Wr)
{
    int b = blockIdx.x;
    const float* src = (b < 256) ? W1 : W2;
    unsigned short* dst = Wr + ((b < 256) ? 0 : 65536);
    int idx = (b & 255) * 256 + threadIdx.x;
    int j  = idx & 7;
    int q  = (idx >> 3) & 3;
    int n  = (idx >> 5) & 255;
    int kc = idx >> 13;
    int p  = kc * 32 + q * 8 + j;
    int k  = (p & ~31) | ((p & 1) << 4) | ((p >> 1) & 15);
    dst[idx] = f2bf(src[k * 256 + n]);
}

// Block i<256: row i of W21' = dt * (W2@W1), fp32, scattered into frag layout.
// Block 256:  c1 = b2@W1 (fp32 vector, unscaled).
__global__ void prep_w21(const float* __restrict__ W1,
                         const float* __restrict__ W2,
                         const float* __restrict__ b2,
                         const float* __restrict__ t_range,
                         unsigned short* __restrict__ W21r,
                         float* __restrict__ c1)
{
    __shared__ float row[256];
    int i = blockIdx.x, j = threadIdx.x;
    row[j] = (i < 256) ? W2[i * 256 + j] : b2[j];
    __syncthreads();
    float acc = 0.f;
    for (int d = 0; d < 256; ++d)
        acc = fmaf(row[d], W1[d * 256 + j], acc);
    if (i < 256) {
        float dt = t_range[1] - t_range[0];
        int p  = (i & ~31) | ((i & 15) << 1) | ((i >> 4) & 1);
        int kc = p >> 5, q = (p >> 3) & 3, jj = p & 7;
        W21r[kc * 8192 + j * 32 + q * 8 + jj] = f2bf(dt * acc);
    } else {
        c1[j] = acc;
    }
}

// 256 threads = 4 waves; wave w owns cols [64w, 64w+64) of the block's 32 rows.
// State: y = z@W1 (omitting c1 drift, folded into bt), S = sum of H.
// Hot loop: stage bf16(H) -> 1 barrier -> one MFMA-GEMM accumulating into y.
__global__ __launch_bounds__(256, 2) void ode_main(
    const float* __restrict__ z0,
    const float* __restrict__ t_range,
    const float* __restrict__ b1,
    const float* __restrict__ wt,
    const float* __restrict__ b2,
    const unsigned short* __restrict__ W1r,
    const unsigned short* __restrict__ W2r,
    const unsigned short* __restrict__ W21r,
    const float* __restrict__ c1,
    float* __restrict__ out)
{
    __shared__ __align__(16) unsigned short As[2 * LDSB];   // 33 KiB double-buffered

    const int tid  = threadIdx.x;
    const int wave = tid >> 6;        // 0..3
    const int lane = tid & 63;
    const int q    = lane >> 4;
    const int l15  = lane & 15;
    const int row0 = blockIdx.x * 32;
    const int n0   = wave * 64;

    const float dt = t_range[1] - t_range[0];

    // bias recurrence: bt_s = b1 + s*dt*(wt + c1); bt_{s+1} = bt_s + dbt
    float bt[4], dbt[4];
#pragma unroll
    for (int tt = 0; tt < 4; ++tt) {
        int n = n0 + tt * 16 + l15;
        bt[tt]  = b1[n];
        dbt[tt] = dt * (wt[n] + c1[n]);
    }

    // ---- stage bf16(z0) into buf0 ----
#pragma unroll
    for (int band = 0; band < 2; ++band)
#pragma unroll
        for (int r = 0; r < 4; ++r) {
            int m = band * 16 + q * 4 + r;
            const float* zr = &z0[(row0 + m) * 256 + n0];
            *(unsigned int*)&As[m * SROW + n0 + l15 * 2] =
                pk2bf(zr[l15], zr[16 + l15]);
            *(unsigned int*)&As[m * SROW + n0 + 32 + l15 * 2] =
                pk2bf(zr[32 + l15], zr[48 + l15]);
        }
    __syncthreads();

    // ---- y0 = z0 @ W1 (B-frags streamed from global, used once) ----
    f32x4 y[2][4];
#pragma unroll
    for (int band = 0; band < 2; ++band)
#pragma unroll
        for (int tt = 0; tt < 4; ++tt) y[band][tt] = f32x4{0.f, 0.f, 0.f, 0.f};
#pragma unroll
    for (int kc = 0; kc < 8; ++kc) {
        bf16x8 a[2];
#pragma unroll
        for (int band = 0; band < 2; ++band)
            a[band] = *(const bf16x8*)&As[(band * 16 + l15) * SROW + kc * 32 + q * 8];
#pragma unroll
        for (int tt = 0; tt < 4; ++tt) {
            bf16x8 bb = *(const bf16x8*)&W1r[kc * 8192 + (n0 + tt * 16 + l15) * 32 + q * 8];
#pragma unroll
            for (int band = 0; band < 2; ++band)
                y[band][tt] = __builtin_amdgcn_mfma_f32_16x16x32_bf16(
                    a[band], bb, y[band][tt], 0, 0, 0);
        }
    }

    // ---- preload W21' fragments (128 VGPRs), resident for the whole loop ----
    bf16x8 w21f[8][4];
#pragma unroll
    for (int kc = 0; kc < 8; ++kc)
#pragma unroll
        for (int tt = 0; tt < 4; ++tt)
            w21f[kc][tt] = *(const bf16x8*)&W21r[kc * 8192 + (n0 + tt * 16 + l15) * 32 + q * 8];

    f32x4 S[2][4];
#pragma unroll
    for (int band = 0; band < 2; ++band)
#pragma unroll
        for (int tt = 0; tt < 4; ++tt) S[band][tt] = f32x4{0.f, 0.f, 0.f, 0.f};

    // ---- 24 full steps: H -> stage -> y += H @ W21' (MFMA-accumulate) ----
    for (int s = 0; s < NSTEP - 1; ++s) {
        const int buf = ((s + 1) & 1) * LDSB;
#pragma unroll
        for (int band = 0; band < 2; ++band)
#pragma unroll
            for (int r = 0; r < 4; ++r) {
                int m = band * 16 + q * 4 + r;
                float h0 = tanh_fast(y[band][0][r] + bt[0]);
                float h1 = tanh_fast(y[band][1][r] + bt[1]);
                float h2 = tanh_fast(y[band][2][r] + bt[2]);
                float h3 = tanh_fast(y[band][3][r] + bt[3]);
                S[band][0][r] += h0; S[band][1][r] += h1;
                S[band][2][r] += h2; S[band][3][r] += h3;
                *(unsigned int*)&As[buf + m * SROW + n0 + l15 * 2]      = pk2bf(h0, h1);
                *(unsigned int*)&As[buf + m * SROW + n0 + 32 + l15 * 2] = pk2bf(h2, h3);
            }
        __syncthreads();

#pragma unroll
        for (int kc = 0; kc < 8; ++kc) {
            bf16x8 a[2];
#pragma unroll
            for (int band = 0; band < 2; ++band)
                a[band] = *(const bf16x8*)&As[buf + (band * 16 + l15) * SROW + kc * 32 + q * 8];
#pragma unroll
            for (int band = 0; band < 2; ++band)
#pragma unroll
                for (int tt = 0; tt < 4; ++tt)
                    y[band][tt] = __builtin_amdgcn_mfma_f32_16x16x32_bf16(
                        a[band], w21f[kc][tt], y[band][tt], 0, 0, 0);
        }

#pragma unroll
        for (int tt = 0; tt < 4; ++tt) bt[tt] += dbt[tt];
    }

    // ---- last step: H only feeds S ----
#pragma unroll
    for (int band = 0; band < 2; ++band)
#pragma unroll
        for (int r = 0; r < 4; ++r)
#pragma unroll
            for (int tt = 0; tt < 4; ++tt)
                S[band][tt][r] += tanh_fast(y[band][tt][r] + bt[tt]);

    // ---- epilogue: z_T = z0 + dt*(S @ W2) + NSTEP*dt*b2 ----
    {
        const int buf = LDSB;   // buf1 (last GEMM at s=23 read buf0)
#pragma unroll
        for (int band = 0; band < 2; ++band)
#pragma unroll
            for (int r = 0; r < 4; ++r) {
                int m = band * 16 + q * 4 + r;
                *(unsigned int*)&As[buf + m * SROW + n0 + l15 * 2] =
                    pk2bf(S[band][0][r], S[band][1][r]);
                *(unsigned int*)&As[buf + m * SROW + n0 + 32 + l15 * 2] =
                    pk2bf(S[band][2][r], S[band][3][r]);
            }
        __syncthreads();

        f32x4 acc[2][4];
#pragma unroll
        for (int band = 0; band < 2; ++band)
#pragma unroll
            for (int tt = 0; tt < 4; ++tt) acc[band][tt] = f32x4{0.f, 0.f, 0.f, 0.f};
#pragma unroll
        for (int kc = 0; kc < 8; ++kc) {
            bf16x8 a[2];
#pragma unroll
            for (int band = 0; band < 2; ++band)
                a[band] = *(const bf16x8*)&As[buf + (band * 16 + l15) * SROW + kc * 32 + q * 8];
#pragma unroll
            for (int tt = 0; tt < 4; ++tt) {
                bf16x8 bb = *(const bf16x8*)&W2r[kc * 8192 + (n0 + tt * 16 + l15) * 32 + q * 8];
#pragma unroll
                for (int band = 0; band < 2; ++band)
                    acc[band][tt] = __builtin_amdgcn_mfma_f32_16x16x32_bf16(
                        a[band], bb, acc[band][tt], 0, 0, 0);
            }
        }

        const float cb2 = (float)NSTEP * dt;
#pragma unroll
        for (int band = 0; band < 2; ++band)
#pragma unroll
            for (int tt = 0; tt < 4; ++tt) {
                float b2v = b2[n0 + tt * 16 + l15];
#pragma unroll
                for (int r = 0; r < 4; ++r) {
                    int idx = (row0 + band * 16 + q * 4 + r) * 256 + n0 + tt * 16 + l15;
                    out[idx] = z0[idx] + dt * acc[band][tt][r] + cb2 * b2v;
                }
            }
    }
}

extern "C" void kernel_launch(void* const* d_in, const int* in_sizes, int n_in,
                              void* d_out, int out_size, void* d_ws, size_t ws_size,
                              hipStream_t stream) {
    const float* z0      = (const float*)d_in[0];
    const float* t_range = (const float*)d_in[1];
    const float* W1      = (const float*)d_in[2];
    const float* b1      = (const float*)d_in[3];
    const float* wt      = (const float*)d_in[4];
    const float* W2      = (const float*)d_in[5];
    const float* b2      = (const float*)d_in[6];

    unsigned short* Wr = (unsigned short*)d_ws;
    // shorts: W1r [0,65536)  W2r [65536,131072)  W21r [131072,196608); then c1 (256 floats)
    unsigned short* W1r  = Wr;
    unsigned short* W2r  = Wr + 65536;
    unsigned short* W21r = Wr + 131072;
    float*          c1   = (float*)(Wr + 196608);

    prep_weights<<<512, 256, 0, stream>>>(W1, W2, Wr);
    prep_w21<<<257, 256, 0, stream>>>(W1, W2, b2, t_range, W21r, c1);
    ode_main<<<512, 256, 0, stream>>>(z0, t_range, b1, wt, b2,
                                      W1r, W2r, W21r, c1, (float*)d_out);
}

// Round 5
// 152.859 us; speedup vs baseline: 2.1780x; 1.0352x over previous
//
#include <hip/hip_runtime.h>

typedef short bf16x8 __attribute__((ext_vector_type(8)));
typedef float f32x4  __attribute__((ext_vector_type(4)));

#define NSTEP 25
#define SROW  264               // padded LDS row stride in shorts
#define LDSB  (32 * SROW)       // shorts per buffer (32 rows)

__device__ __forceinline__ unsigned short f2bf(float x) {
    union { float f; unsigned int u; } v; v.f = x;
    unsigned int r = v.u + 0x7FFFu + ((v.u >> 16) & 1u);   // RNE
    return (unsigned short)(r >> 16);
}

#if __has_builtin(__builtin_amdgcn_cvt_pk_bf16_f32)
typedef __bf16 bfv2 __attribute__((ext_vector_type(2)));
__device__ __forceinline__ unsigned int pk2bf(float a, float b) {
    union { bfv2 v; unsigned int u; } c;
    c.v = __builtin_amdgcn_cvt_pk_bf16_f32(a, b);   // lo=a, hi=b, RNE
    return c.u;
}
#else
__device__ __forceinline__ unsigned int pk2bf(float a, float b) {
    return (unsigned int)f2bf(a) | ((unsigned int)f2bf(b) << 16);
}
#endif

__device__ __forceinline__ float tanh_fast(float x) {
    float e = __expf(2.0f * x);
    return 1.0f - 2.0f * __builtin_amdgcn_rcpf(e + 1.0f);
}

// One prep dispatch:
//  b in [0,512):  sigma-permuted fragment-ordered bf16 W1r/W2r
//                 (coalesced READ of W[k][n], scattered store)
//  b in [512,769): W21' = dt*(W2@W1) rows -> frag layout; b==768 -> c1 = b2@W1
// Layout (verified R2-R4): Wr[kc*8192 + n*32 + q*8 + j] = W[sigma_inv(kc*32+q*8+j)][n]
// sigma_inv(p) = (p & ~31) | ((p&1)<<4) | ((p>>1)&15);  forward:
// sigma(k)     = (k & ~31) | ((k&15)<<1) | ((k>>4)&1)
__global__ void prep_all(const float* __restrict__ W1,
                         const float* __restrict__ W2,
                         const float* __restrict__ b2,
                         const float* __restrict__ t_range,
                         unsigned short* __restrict__ Wr,
                         unsigned short* __restrict__ W21r,
                         float* __restrict__ c1)
{
    __shared__ float row[256];
    int b = blockIdx.x;
    if (b < 512) {
        // source-coalesced: this block handles source row k = b&255 of W1 or W2
        const float* src = (b < 256) ? W1 : W2;
        unsigned short* dst = Wr + ((b < 256) ? 0 : 65536);
        int k = b & 255;
        int n = threadIdx.x;
        int p  = (k & ~31) | ((k & 15) << 1) | ((k >> 4) & 1);
        int kc = p >> 5, q = (p >> 3) & 3, j = p & 7;
        dst[kc * 8192 + n * 32 + q * 8 + j] = f2bf(src[k * 256 + n]);
    } else {
        int i = b - 512, j = threadIdx.x;
        row[j] = (i < 256) ? W2[i * 256 + j] : b2[j];
        __syncthreads();
        float acc = 0.f;
        for (int d = 0; d < 256; ++d)
            acc = fmaf(row[d], W1[d * 256 + j], acc);
        if (i < 256) {
            float dt = t_range[1] - t_range[0];
            int p  = (i & ~31) | ((i & 15) << 1) | ((i >> 4) & 1);
            int kc = p >> 5, q = (p >> 3) & 3, jj = p & 7;
            W21r[kc * 8192 + j * 32 + q * 8 + jj] = f2bf(dt * acc);
        } else {
            c1[j] = acc;
        }
    }
}

// 512 threads = 8 waves; wave w owns cols [32w, 32w+32) of the block's 32 rows.
// w21f = 64 VGPRs -> fits 128-reg budget -> 4 waves/SIMD (16 waves/CU).
// State: y = z@W1 (c1 drift folded into bt), S = sum of H.
// Hot loop: tanh+stage bf16(H) -> 1 barrier -> y += H @ W21' (MFMA-accumulate).
__global__ __launch_bounds__(512, 4) void ode_main(
    const float* __restrict__ z0,
    const float* __restrict__ t_range,
    const float* __restrict__ b1,
    const float* __restrict__ wt,
    const float* __restrict__ b2,
    const unsigned short* __restrict__ W1r,
    const unsigned short* __restrict__ W2r,
    const unsigned short* __restrict__ W21r,
    const float* __restrict__ c1,
    float* __restrict__ out)
{
    __shared__ __align__(16) unsigned short As[2 * LDSB];   // 33 KiB double-buffered

    const int tid  = threadIdx.x;
    const int wave = tid >> 6;        // 0..7
    const int lane = tid & 63;
    const int q    = lane >> 4;
    const int l15  = lane & 15;
    const int row0 = blockIdx.x * 32;
    const int n0   = wave * 32;

    const float dt = t_range[1] - t_range[0];

    // bias recurrence: bt_s = b1 + s*dt*(wt + c1); bt_{s+1} = bt_s + dbt
    float bt[2], dbt[2];
#pragma unroll
    for (int tt = 0; tt < 2; ++tt) {
        int n = n0 + tt * 16 + l15;
        bt[tt]  = b1[n];
        dbt[tt] = dt * (wt[n] + c1[n]);
    }

    // ---- stage bf16(z0) into buf0 ----
#pragma unroll
    for (int band = 0; band < 2; ++band)
#pragma unroll
        for (int r = 0; r < 4; ++r) {
            int m = band * 16 + q * 4 + r;
            const float* zr = &z0[(row0 + m) * 256 + n0];
            *(unsigned int*)&As[m * SROW + n0 + l15 * 2] =
                pk2bf(zr[l15], zr[16 + l15]);
        }
    __syncthreads();

    // ---- y0 = z0 @ W1 (B-frags streamed from global, used once) ----
    f32x4 y[2][2];
#pragma unroll
    for (int band = 0; band < 2; ++band)
#pragma unroll
        for (int tt = 0; tt < 2; ++tt) y[band][tt] = f32x4{0.f, 0.f, 0.f, 0.f};
#pragma unroll
    for (int kc = 0; kc < 8; ++kc) {
        bf16x8 a[2];
#pragma unroll
        for (int band = 0; band < 2; ++band)
            a[band] = *(const bf16x8*)&As[(band * 16 + l15) * SROW + kc * 32 + q * 8];
#pragma unroll
        for (int tt = 0; tt < 2; ++tt) {
            bf16x8 bb = *(const bf16x8*)&W1r[kc * 8192 + (n0 + tt * 16 + l15) * 32 + q * 8];
#pragma unroll
            for (int band = 0; band < 2; ++band)
                y[band][tt] = __builtin_amdgcn_mfma_f32_16x16x32_bf16(
                    a[band], bb, y[band][tt], 0, 0, 0);
        }
    }

    // ---- preload W21' fragments (64 VGPRs), resident for the whole loop ----
    bf16x8 w21f[8][2];
#pragma unroll
    for (int kc = 0; kc < 8; ++kc)
#pragma unroll
        for (int tt = 0; tt < 2; ++tt)
            w21f[kc][tt] = *(const bf16x8*)&W21r[kc * 8192 + (n0 + tt * 16 + l15) * 32 + q * 8];

    f32x4 S[2][2];
#pragma unroll
    for (int band = 0; band < 2; ++band)
#pragma unroll
        for (int tt = 0; tt < 2; ++tt) S[band][tt] = f32x4{0.f, 0.f, 0.f, 0.f};

    // ---- 24 full steps: H -> stage -> y += H @ W21' (MFMA-accumulate) ----
    for (int s = 0; s < NSTEP - 1; ++s) {
        const int buf = ((s + 1) & 1) * LDSB;
#pragma unroll
        for (int band = 0; band < 2; ++band)
#pragma unroll
            for (int r = 0; r < 4; ++r) {
                int m = band * 16 + q * 4 + r;
                float h0 = tanh_fast(y[band][0][r] + bt[0]);
                float h1 = tanh_fast(y[band][1][r] + bt[1]);
                S[band][0][r] += h0; S[band][1][r] += h1;
                *(unsigned int*)&As[buf + m * SROW + n0 + l15 * 2] = pk2bf(h0, h1);
            }
        __syncthreads();

#pragma unroll
        for (int kc = 0; kc < 8; ++kc) {
            bf16x8 a[2];
#pragma unroll
            for (int band = 0; band < 2; ++band)
                a[band] = *(const bf16x8*)&As[buf + (band * 16 + l15) * SROW + kc * 32 + q * 8];
#pragma unroll
            for (int band = 0; band < 2; ++band)
#pragma unroll
                for (int tt = 0; tt < 2; ++tt)
                    y[band][tt] = __builtin_amdgcn_mfma_f32_16x16x32_bf16(
                        a[band], w21f[kc][tt], y[band][tt], 0, 0, 0);
        }

#pragma unroll
        for (int tt = 0; tt < 2; ++tt) bt[tt] += dbt[tt];
    }

    // ---- last step: H only feeds S ----
#pragma unroll
    for (int band = 0; band < 2; ++band)
#pragma unroll
        for (int r = 0; r < 4; ++r)
#pragma unroll
            for (int tt = 0; tt < 2; ++tt)
                S[band][tt][r] += tanh_fast(y[band][tt][r] + bt[tt]);

    // ---- epilogue: z_T = z0 + dt*(S @ W2) + NSTEP*dt*b2 ----
    {
        const int buf = LDSB;   // buf1 (last GEMM at s=23 read buf0)
#pragma unroll
        for (int band = 0; band < 2; ++band)
#pragma unroll
            for (int r = 0; r < 4; ++r) {
                int m = band * 16 + q * 4 + r;
                *(unsigned int*)&As[buf + m * SROW + n0 + l15 * 2] =
                    pk2bf(S[band][0][r], S[band][1][r]);
            }
        __syncthreads();

        f32x4 acc[2][2];
#pragma unroll
        for (int band = 0; band < 2; ++band)
#pragma unroll
            for (int tt = 0; tt < 2; ++tt) acc[band][tt] = f32x4{0.f, 0.f, 0.f, 0.f};
#pragma unroll
        for (int kc = 0; kc < 8; ++kc) {
            bf16x8 a[2];
#pragma unroll
            for (int band = 0; band < 2; ++band)
                a[band] = *(const bf16x8*)&As[buf + (band * 16 + l15) * SROW + kc * 32 + q * 8];
#pragma unroll
            for (int tt = 0; tt < 2; ++tt) {
                bf16x8 bb = *(const bf16x8*)&W2r[kc * 8192 + (n0 + tt * 16 + l15) * 32 + q * 8];
#pragma unroll
                for (int band = 0; band < 2; ++band)
                    acc[band][tt] = __builtin_amdgcn_mfma_f32_16x16x32_bf16(
                        a[band], bb, acc[band][tt], 0, 0, 0);
            }
        }

        const float cb2 = (float)NSTEP * dt;
#pragma unroll
        for (int band = 0; band < 2; ++band)
#pragma unroll
            for (int tt = 0; tt < 2; ++tt) {
                float b2v = b2[n0 + tt * 16 + l15];
#pragma unroll
                for (int r = 0; r < 4; ++r) {
                    int idx = (row0 + band * 16 + q * 4 + r) * 256 + n0 + tt * 16 + l15;
                    out[idx] = z0[idx] + dt * acc[band][tt][r] + cb2 * b2v;
                }
            }
    }
}

extern "C" void kernel_launch(void* const* d_in, const int* in_sizes, int n_in,
                              void* d_out, int out_size, void* d_ws, size_t ws_size,
                              hipStream_t stream) {
    const float* z0      = (const float*)d_in[0];
    const float* t_range = (const float*)d_in[1];
    const float* W1      = (const float*)d_in[2];
    const float* b1      = (const float*)d_in[3];
    const float* wt      = (const float*)d_in[4];
    const float* W2      = (const float*)d_in[5];
    const float* b2      = (const float*)d_in[6];

    unsigned short* Wr = (unsigned short*)d_ws;
    // shorts: W1r [0,65536)  W2r [65536,131072)  W21r [131072,196608); then c1 (256 floats)
    unsigned short* W1r  = Wr;
    unsigned short* W2r  = Wr + 65536;
    unsigned short* W21r = Wr + 131072;
    float*          c1   = (float*)(Wr + 196608);

    prep_all<<<769, 256, 0, stream>>>(W1, W2, b2, t_range, Wr, W21r, c1);
    ode_main<<<512, 512, 0, stream>>>(z0, t_range, b1, wt, b2,
                                      W1r, W2r, W21r, c1, (float*)d_out);
}